// Round 6
// baseline (621.471 us; speedup 1.0000x reference)
//
#include <hip/hip_runtime.h>

typedef unsigned int uint;
typedef unsigned short ushort_t;
typedef ushort_t ushort8 __attribute__((ext_vector_type(8)));
typedef ushort_t ushort4v __attribute__((ext_vector_type(4)));
typedef short short8 __attribute__((ext_vector_type(8)));
typedef float floatx4 __attribute__((ext_vector_type(4)));
typedef uint uint2v __attribute__((ext_vector_type(2)));
typedef uint uint4v __attribute__((ext_vector_type(4)));

#define WSQ 25165824L   // elements per q/k/v tensor: 256*12*256*32
#define NH  12
#define NT  256
#define HD  32

__device__ __forceinline__ float bf2f(ushort_t u) {
    uint x = ((uint)u) << 16;
    return __builtin_bit_cast(float, x);
}
__device__ __forceinline__ ushort_t f2bf(float f) {
    uint u = __builtin_bit_cast(uint, f);
    uint lsb = (u >> 16) & 1u;
    return (ushort_t)((u + 0x7FFFu + lsb) >> 16);
}
// packed f32x2 -> bf16x2 (RNE in HW), 1 inst instead of ~8
__device__ __forceinline__ uint cvt_pk_bf16(float lo, float hi) {
    uint r;
    asm("v_cvt_pk_bf16_f32 %0, %1, %2" : "=v"(r) : "v"(lo), "v"(hi));
    return r;
}
__device__ __forceinline__ float exp2_fast(float x) {
    float r;
    asm("v_exp_f32 %0, %1" : "=v"(r) : "v"(x));
    return r;
}
// gfx950 cross-lane row swaps via verified builtins (return {new_a, new_b}).
// 32-swap: a[32:63] <-> b[0:31].  16-swap: a[16:31]<->b[0:15], a[48:63]<->b[32:47].
__device__ __forceinline__ void permlane32_swap(uint& a, uint& b) {
    uint2v r = __builtin_amdgcn_permlane32_swap(a, b, false, false);
    a = r[0]; b = r[1];
}
__device__ __forceinline__ void permlane16_swap(uint& a, uint& b) {
    uint2v r = __builtin_amdgcn_permlane16_swap(a, b, false, false);
    a = r[0]; b = r[1];
}
__device__ __forceinline__ float ld1(const void* p, long i, int f) {
    return f ? ((const float*)p)[i] : bf2f(((const ushort_t*)p)[i]);
}
// load 8 elements as bf16, converting from f32 on the fly (fused cvt staging)
__device__ __forceinline__ ushort8 ld_bf8(const void* p, long idx, int f) {
    if (f) {
        const floatx4* s = (const floatx4*)((const float*)p + idx);
        floatx4 a = s[0], b = s[1];
        uint4v u;
        u[0] = cvt_pk_bf16(a[0], a[1]); u[1] = cvt_pk_bf16(a[2], a[3]);
        u[2] = cvt_pk_bf16(b[0], b[1]); u[3] = cvt_pk_bf16(b[2], b[3]);
        return __builtin_bit_cast(ushort8, u);
    }
    return *(const ushort8*)((const ushort_t*)p + idx);
}

// ---------------- dtype detection: 1 wave ----------------
__global__ void detect_kernel(const ushort_t* __restrict__ x, int* __restrict__ flag) {
    int t = threadIdx.x;                 // 64 threads
    uint u = x[2 * t];                   // low half if f32, element 2t if bf16
    int e = (u >> 7) & 0xFF;
    int weird = (e > 147 || e < 107) ? 1 : 0;   // |exp-127| > 20
    unsigned long long b = __ballot(weird);
    if (t == 0) *flag = (__popcll(b) > 19) ? 1 : 0;   // >30% weird -> f32
}

// ---------------- CPB MLP: 2 -> 512 -> 12 ----------------
__global__ __launch_bounds__(512) void cpb_kernel(
    const void* __restrict__ tab, const void* __restrict__ w1,
    const void* __restrict__ b1, const void* __restrict__ w2,
    const int* __restrict__ fl, float* __restrict__ bt)
{
    __shared__ float hid[512];
    const int f = *fl;
    int p = blockIdx.x, j = threadIdx.x;
    float c0 = ld1(tab, p * 2 + 0, f);
    float c1 = ld1(tab, p * 2 + 1, f);
    float v = ld1(w1, j * 2 + 0, f) * c0 + ld1(w1, j * 2 + 1, f) * c1 + ld1(b1, j, f);
    hid[j] = fmaxf(v, 0.0f);
    __syncthreads();
    if (j < NH) {
        float s = 0.0f;
        for (int i = 0; i < 512; ++i) s += hid[i] * ld1(w2, (long)j * 512 + i, f);
        bt[p * NH + j] = s;
    }
}

// ---------------- rpb gather + 16*sigmoid, log2 domain, bound-shifted ----------------
// Stores rpb' = 16*sigmoid(x)*log2e - B_h, with B_h = min(scale_h,40)*1.02 + 23.1.
// For scale<=40 the attn fast path uses exp2(S*scale + rpb') directly (no max pass):
// the argument is provably <= 0 and >= -105, so no overflow/underflow. For scale>40
// the attn fallback computes an exact max (uniform shift cancels).
__global__ __launch_bounds__(256) void rpb_kernel(
    const int* __restrict__ rpi, const float* __restrict__ bt,
    const void* __restrict__ ls, const int* __restrict__ fl,
    float* __restrict__ rpb)
{
    int idx = blockIdx.x * 256 + threadIdx.x;      // 12*65536 total
    int h = idx >> 16, ij = idx & 65535;
    float x = bt[rpi[ij] * NH + h];
    float scale = __expf(fminf(ld1(ls, h, *fl), 4.6051702f)) * 1.44269504f;
    float bound = fminf(scale, 40.0f) * 1.02f + 23.1f;
    rpb[idx] = 1.44269504f * 16.0f / (1.0f + __expf(-x)) - bound;
}

// ---------------- GEMM C = A[M,384] @ W[N,384]^T + bias ----------------
// MODE 0: qkv projection: A = x (f32 OR bf16 -- cvt fused into staging),
//         scatter-store bf16 [which][B,H,N,32]
// MODE 1: out projection: A = attn overlay in qkv q-region (always bf16),
//         store dual-dtype to d_out
// B (weights) also staged with fused cvt. 1D grid + bijective XCD-chunk swizzle:
// each XCD owns a contiguous m-range (n fastest within chunk) so each A-slab is
// fetched by exactly ONE XCD and L2-reused; B stays L2-resident per XCD.
template <int MODE>
__global__ __launch_bounds__(256) void gemm_bt(
    const void* __restrict__ A, const void* __restrict__ Bw,
    const void* __restrict__ bias0, const void* __restrict__ bias2,
    void* __restrict__ Cout, const int* __restrict__ fl)
{
    const int K = 384;
    const int NBX = (MODE == 0) ? 9 : 3;        // n-blocks
    const int CHUNK = NBX * 512 / 8;            // blocks per XCD (576 / 192, both exact)
    __shared__ ushort_t As[128 * 72];
    __shared__ ushort_t Bs[128 * 72];
    const int f = *fl;
    const int tid = threadIdx.x;
    const int w = tid >> 6, lane = tid & 63, l15 = lane & 15, quad = lane >> 4;
    const int bid = blockIdx.x;
    const int wg = (bid & 7) * CHUNK + (bid >> 3);
    const int m0 = (wg / NBX) * 128, n0 = (wg % NBX) * 128;
    const int rw = (w >> 1) * 64, cw = (w & 1) * 64;
    const int lr = tid >> 3, lc = (tid & 7) * 8;

    floatx4 acc[4][4] = {};
    ushort8 pa[4], pb[4];

    // prefetch K-tile 0 (with fused dtype convert)
    for (int i = 0; i < 4; ++i) {
        int r = lr + i * 32;
        if (MODE == 0) {
            pa[i] = ld_bf8(A, (long)(m0 + r) * K + lc, f);
        } else {
            int m = m0 + r, kc = lc;
            long ad = ((long)(m >> 8) * 12 + (kc >> 5)) * 8192 + (m & 255) * 32 + (kc & 31);
            pa[i] = *(const ushort8*)&((const ushort_t*)A)[ad];
        }
        pb[i] = ld_bf8(Bw, (long)(n0 + r) * K + lc, f);
    }

    for (int kt = 0; kt < K; kt += 64) {
        for (int i = 0; i < 4; ++i) {
            int r = lr + i * 32;
            *(ushort8*)&As[r * 72 + lc] = pa[i];
            *(ushort8*)&Bs[r * 72 + lc] = pb[i];
        }
        __syncthreads();
        if (kt + 64 < K) {
            for (int i = 0; i < 4; ++i) {
                int r = lr + i * 32;
                if (MODE == 0) {
                    pa[i] = ld_bf8(A, (long)(m0 + r) * K + kt + 64 + lc, f);
                } else {
                    int m = m0 + r, kc = kt + 64 + lc;
                    long ad = ((long)(m >> 8) * 12 + (kc >> 5)) * 8192 + (m & 255) * 32 + (kc & 31);
                    pa[i] = *(const ushort8*)&((const ushort_t*)A)[ad];
                }
                pb[i] = ld_bf8(Bw, (long)(n0 + r) * K + kt + 64 + lc, f);
            }
        }
        for (int ks = 0; ks < 64; ks += 32) {
            short8 af[4], bfr[4];
            for (int mt = 0; mt < 4; ++mt)
                af[mt] = *(short8*)&As[(rw + mt * 16 + l15) * 72 + ks + quad * 8];
            for (int nt = 0; nt < 4; ++nt)
                bfr[nt] = *(short8*)&Bs[(cw + nt * 16 + l15) * 72 + ks + quad * 8];
            __builtin_amdgcn_s_setprio(1);
            for (int mt = 0; mt < 4; ++mt)
                for (int nt = 0; nt < 4; ++nt)
                    acc[mt][nt] = __builtin_amdgcn_mfma_f32_16x16x32_bf16(
                        af[mt], bfr[nt], acc[mt][nt], 0, 0, 0);
            __builtin_amdgcn_s_setprio(0);
        }
        __syncthreads();
    }

    for (int mt = 0; mt < 4; ++mt) {
        for (int nt = 0; nt < 4; ++nt) {
            int c = n0 + cw + nt * 16 + l15;
            if (MODE == 0) {
                int which = c / 384, cc = c % 384;
                float bias = (which == 0) ? ld1(bias0, cc, f)
                           : (which == 2) ? ld1(bias2, cc, f) : 0.0f;
                int hh = cc >> 5, dd = cc & 31;
                for (int r = 0; r < 4; ++r) {
                    int m = m0 + rw + mt * 16 + quad * 4 + r;
                    int b = m >> 8, ntok = m & 255;
                    long dst = (long)which * WSQ +
                               (((long)(b * NH + hh) * NT + ntok) * HD + dd);
                    ((ushort_t*)Cout)[dst] = f2bf(acc[mt][nt][r] + bias);
                }
            } else {
                float bias = ld1(bias0, c, f);
                for (int r = 0; r < 4; ++r) {
                    int m = m0 + rw + mt * 16 + quad * 4 + r;
                    float v = acc[mt][nt][r] + bias;
                    long o = (long)m * 384 + c;
                    if (f) ((float*)Cout)[o] = v;
                    else   ((ushort_t*)Cout)[o] = f2bf(v);
                }
            }
        }
    }
}

// ---------------- fused window attention: one block per (b,h), 256 thr / 4 waves ----------------
// Single-pass softmax: rpb is pre-shifted by -B_h, so p = exp2(fmaf(S,scale,rpb'))
// comes straight off the S^T MFMA output (no max pass, no cross-lane max reduce).
// P never touches LDS (cvt_pk + permlane quad-transpose). LDS = ks + vts (37,376 B)
// -> 4 blocks/CU x 4 waves. setprio(1) around MFMA clusters (waves are barrier-free
// and phase-staggered -> scheduler can favor the MFMA-issuing wave).
__global__ __launch_bounds__(256, 4) void attn_kernel(
    ushort_t* __restrict__ qkv, const void* __restrict__ ls,
    const float* __restrict__ rpb, const int* __restrict__ fl)
{
    __shared__ __attribute__((aligned(16))) ushort_t ks[256 * 40];    // 20480 B
    __shared__ __attribute__((aligned(16))) ushort_t vts[32 * 264];   // 16896 B

    const int f = *fl;
    // bijective: 3072 = 8 XCD x (12 h x 32 windows); same-h blocks contiguous per XCD
    const int bid = blockIdx.x;
    const int xcd = bid & 7, local = bid >> 3;
    const int h = local >> 5, bwin = (xcd << 5) + (local & 31);
    const int bh = bwin * NH + h;
    ushort_t* qp = qkv + (long)bh * NT * HD;
    const ushort_t* kp = qp + WSQ;
    const ushort_t* vp = qp + 2 * WSQ;
    const int tid = threadIdx.x;
    // logit scale, log2 domain (matches pre-scaled rpb)
    const float scale = __expf(fminf(ld1(ls, h, f), 4.6051702f)) * 1.44269504f;

    // ---- stage K (L2-normalized) and V^T: one token per thread ----
    {
        const int t = tid;
        ushort8 kv[4];
        #pragma unroll
        for (int i = 0; i < 4; ++i) kv[i] = *(const ushort8*)&kp[t * HD + i * 8];
        float fv[32]; float ss = 0.0f;
        #pragma unroll
        for (int i = 0; i < 4; ++i)
            #pragma unroll
            for (int j = 0; j < 8; ++j) {
                float v = bf2f(kv[i][j]); fv[i * 8 + j] = v; ss += v * v;
            }
        float rn = 1.0f / fmaxf(sqrtf(ss), 1e-12f);
        #pragma unroll
        for (int i = 0; i < 4; ++i) {
            uint4v o;
            #pragma unroll
            for (int j = 0; j < 4; ++j)
                o[j] = cvt_pk_bf16(fv[i * 8 + 2 * j] * rn, fv[i * 8 + 2 * j + 1] * rn);
            *(uint4v*)&ks[t * 40 + i * 8] = o;
        }
        ushort8 vv[4];
        #pragma unroll
        for (int i = 0; i < 4; ++i) vv[i] = *(const ushort8*)&vp[t * HD + i * 8];
        #pragma unroll
        for (int i = 0; i < 4; ++i)
            #pragma unroll
            for (int j = 0; j < 8; ++j) vts[(i * 8 + j) * 264 + t] = vv[i][j];
    }
    __syncthreads();

    const int w = tid >> 6, lane = tid & 63, l15 = lane & 15, quad = lane >> 4;

    if (scale <= 40.0f) {
      // ================= fast path: bound-shifted single-pass softmax =================
      for (int c = 0; c < 4; ++c) {
        const int mloc = w * 64 + c * 16;

        // q fragment: lane holds q[mloc+l15][quad*8..+8]; normalize via shfl
        ushort8 qv = *(const ushort8*)&qp[(mloc + l15) * HD + quad * 8];
        float qf[8]; float ss = 0.0f;
        #pragma unroll
        for (int j = 0; j < 8; ++j) { qf[j] = bf2f(qv[j]); ss += qf[j] * qf[j]; }
        ss += __shfl_xor(ss, 16, 64);
        ss += __shfl_xor(ss, 32, 64);
        float rn = 1.0f / fmaxf(sqrtf(ss), 1e-12f);
        uint4v qa;
        #pragma unroll
        for (int j = 0; j < 4; ++j)
            qa[j] = cvt_pk_bf16(qf[2 * j] * rn, qf[2 * j + 1] * rn);
        short8 aq = __builtin_bit_cast(short8, qa);

        // S^T strip: MFMA(A=k, B=q) -> D[key][token]; lane: token=l15, keys=t*16+quad*4+r
        floatx4 accS[16];
        __builtin_amdgcn_s_setprio(1);
        #pragma unroll
        for (int t = 0; t < 16; ++t) {
            short8 bk = *(short8*)&ks[(t * 16 + l15) * 40 + quad * 8];
            floatx4 z = {};
            accS[t] = __builtin_amdgcn_mfma_f32_16x16x32_bf16(bk, aq, z, 0, 0, 0);
        }
        __builtin_amdgcn_s_setprio(0);

        const float* rp = rpb + ((long)h * NT + mloc + l15) * NT;
        const floatx4* rp4 = (const floatx4*)rp;   // strip t, quad -> rp4[t*4+quad]

        // 8 PV phases: fused exp2(fmaf(S,scale,rpb')) + pack + permlane + 2 MFMA.
        // rpb loads prefetched one phase ahead; everything pipelines with MFMA.
        float s4[4] = {0.f, 0.f, 0.f, 0.f};
        floatx4 accO[2] = {};
        floatx4 rb0 = rp4[quad], rb1 = rp4[4 + quad];
        #pragma unroll
        for (int kk = 0; kk < 8; ++kk) {
            short8 vf0 = *(short8*)&vts[l15 * 264 + kk * 32 + quad * 8];
            short8 vf1 = *(short8*)&vts[(16 + l15) * 264 + kk * 32 + quad * 8];
            floatx4 nb0 = rb0, nb1 = rb1;
            if (kk < 7) { nb0 = rp4[8 * (kk + 1) + quad]; nb1 = rp4[8 * (kk + 1) + 4 + quad]; }
            const int t0 = 2 * kk, t1 = 2 * kk + 1;
            float a0 = exp2_fast(fmaf(accS[t0][0], scale, rb0[0]));
            float a1 = exp2_fast(fmaf(accS[t0][1], scale, rb0[1]));
            float a2 = exp2_fast(fmaf(accS[t0][2], scale, rb0[2]));
            float a3 = exp2_fast(fmaf(accS[t0][3], scale, rb0[3]));
            float e0 = exp2_fast(fmaf(accS[t1][0], scale, rb1[0]));
            float e1 = exp2_fast(fmaf(accS[t1][1], scale, rb1[1]));
            float e2 = exp2_fast(fmaf(accS[t1][2], scale, rb1[2]));
            float e3 = exp2_fast(fmaf(accS[t1][3], scale, rb1[3]));
            s4[0] += a0 + e0; s4[1] += a1 + e1;
            s4[2] += a2 + e2; s4[3] += a3 + e3;
            uint A0 = cvt_pk_bf16(a0, a1), A1 = cvt_pk_bf16(a2, a3);
            uint B0 = cvt_pk_bf16(e0, e1), B1 = cvt_pk_bf16(e2, e3);
            permlane32_swap(A0, B0); permlane16_swap(A0, B0);
            permlane32_swap(A1, B1); permlane16_swap(A1, B1);
            uint4v pw; pw[0] = A0; pw[1] = A1; pw[2] = B0; pw[3] = B1;
            short8 pf = __builtin_bit_cast(short8, pw);
            __builtin_amdgcn_s_setprio(1);
            accO[0] = __builtin_amdgcn_mfma_f32_16x16x32_bf16(pf, vf0, accO[0], 0, 0, 0);
            accO[1] = __builtin_amdgcn_mfma_f32_16x16x32_bf16(pf, vf1, accO[1], 0, 0, 0);
            __builtin_amdgcn_s_setprio(0);
            rb0 = nb0; rb1 = nb1;
        }

        float rsum = (s4[0] + s4[1]) + (s4[2] + s4[3]);
        rsum += __shfl_xor(rsum, 16, 64);
        rsum += __shfl_xor(rsum, 32, 64);
        float rinv = 1.0f / rsum;
        float ri[4];
        #pragma unroll
        for (int r = 0; r < 4; ++r) ri[r] = __shfl(rinv, quad * 4 + r, 64);

        // epilogue: D[token=quad*4+r][d=tn*16+l15], fold 1/rsum here
        #pragma unroll
        for (int tn = 0; tn < 2; ++tn)
            #pragma unroll
            for (int r = 0; r < 4; r += 2) {
                uint pk = cvt_pk_bf16(accO[tn][r] * ri[r], accO[tn][r + 1] * ri[r + 1]);
                int n = mloc + quad * 4 + r;
                qp[n * HD + tn * 16 + l15] = (ushort_t)pk;
                qp[(n + 1) * HD + tn * 16 + l15] = (ushort_t)(pk >> 16);
            }
      }
    } else {
      // ============ exact-max fallback (scale>40; uniform rpb shift cancels) ============
      for (int c = 0; c < 4; ++c) {
        const int mloc = w * 64 + c * 16;

        ushort8 qv = *(const ushort8*)&qp[(mloc + l15) * HD + quad * 8];
        float qf[8]; float ss = 0.0f;
        #pragma unroll
        for (int j = 0; j < 8; ++j) { qf[j] = bf2f(qv[j]); ss += qf[j] * qf[j]; }
        ss += __shfl_xor(ss, 16, 64);
        ss += __shfl_xor(ss, 32, 64);
        float rn = 1.0f / fmaxf(sqrtf(ss), 1e-12f);
        uint4v qa;
        #pragma unroll
        for (int j = 0; j < 4; ++j)
            qa[j] = cvt_pk_bf16(qf[2 * j] * rn, qf[2 * j + 1] * rn);
        short8 aq = __builtin_bit_cast(short8, qa);

        floatx4 accS[16];
        #pragma unroll
        for (int t = 0; t < 16; ++t) {
            short8 bk = *(short8*)&ks[(t * 16 + l15) * 40 + quad * 8];
            floatx4 z = {};
            accS[t] = __builtin_amdgcn_mfma_f32_16x16x32_bf16(bk, aq, z, 0, 0, 0);
        }

        const float* rp = rpb + ((long)h * NT + mloc + l15) * NT;
        float m4[4] = {-3e38f, -3e38f, -3e38f, -3e38f};
        #pragma unroll
        for (int t = 0; t < 16; ++t) {
            floatx4 rb = *(const floatx4*)&rp[t * 16 + quad * 4];
            float v0 = fmaf(accS[t][0], scale, rb[0]);
            float v1 = fmaf(accS[t][1], scale, rb[1]);
            float v2 = fmaf(accS[t][2], scale, rb[2]);
            float v3 = fmaf(accS[t][3], scale, rb[3]);
            accS[t][0] = v0; accS[t][1] = v1; accS[t][2] = v2; accS[t][3] = v3;
            m4[t & 3] = fmaxf(m4[t & 3], fmaxf(fmaxf(v0, v1), fmaxf(v2, v3)));
        }
        float rmax = fmaxf(fmaxf(m4[0], m4[1]), fmaxf(m4[2], m4[3]));
        rmax = fmaxf(rmax, __shfl_xor(rmax, 16, 64));
        rmax = fmaxf(rmax, __shfl_xor(rmax, 32, 64));

        float s4[4] = {0.f, 0.f, 0.f, 0.f};
        floatx4 accO[2] = {};
        #pragma unroll
        for (int kk = 0; kk < 8; ++kk) {
            short8 vf0 = *(short8*)&vts[l15 * 264 + kk * 32 + quad * 8];
            short8 vf1 = *(short8*)&vts[(16 + l15) * 264 + kk * 32 + quad * 8];
            const int t0 = 2 * kk, t1 = 2 * kk + 1;
            float a0 = exp2_fast(accS[t0][0] - rmax);
            float a1 = exp2_fast(accS[t0][1] - rmax);
            float a2 = exp2_fast(accS[t0][2] - rmax);
            float a3 = exp2_fast(accS[t0][3] - rmax);
            float e0 = exp2_fast(accS[t1][0] - rmax);
            float e1 = exp2_fast(accS[t1][1] - rmax);
            float e2 = exp2_fast(accS[t1][2] - rmax);
            float e3 = exp2_fast(accS[t1][3] - rmax);
            s4[0] += a0 + e0; s4[1] += a1 + e1;
            s4[2] += a2 + e2; s4[3] += a3 + e3;
            uint A0 = cvt_pk_bf16(a0, a1), A1 = cvt_pk_bf16(a2, a3);
            uint B0 = cvt_pk_bf16(e0, e1), B1 = cvt_pk_bf16(e2, e3);
            permlane32_swap(A0, B0); permlane16_swap(A0, B0);
            permlane32_swap(A1, B1); permlane16_swap(A1, B1);
            uint4v pw; pw[0] = A0; pw[1] = A1; pw[2] = B0; pw[3] = B1;
            short8 pf = __builtin_bit_cast(short8, pw);
            accO[0] = __builtin_amdgcn_mfma_f32_16x16x32_bf16(pf, vf0, accO[0], 0, 0, 0);
            accO[1] = __builtin_amdgcn_mfma_f32_16x16x32_bf16(pf, vf1, accO[1], 0, 0, 0);
        }

        float rsum = (s4[0] + s4[1]) + (s4[2] + s4[3]);
        rsum += __shfl_xor(rsum, 16, 64);
        rsum += __shfl_xor(rsum, 32, 64);
        float rinv = 1.0f / rsum;
        float ri[4];
        #pragma unroll
        for (int r = 0; r < 4; ++r) ri[r] = __shfl(rinv, quad * 4 + r, 64);

        #pragma unroll
        for (int tn = 0; tn < 2; ++tn)
            #pragma unroll
            for (int r = 0; r < 4; r += 2) {
                uint pk = cvt_pk_bf16(accO[tn][r] * ri[r], accO[tn][r + 1] * ri[r + 1]);
                int n = mloc + quad * 4 + r;
                qp[n * HD + tn * 16 + l15] = (ushort_t)pk;
                qp[(n + 1) * HD + tn * 16 + l15] = (ushort_t)(pk >> 16);
            }
      }
    }
}

extern "C" void kernel_launch(void* const* d_in, const int* in_sizes, int n_in,
                              void* d_out, int out_size, void* d_ws, size_t ws_size,
                              hipStream_t stream)
{
    const void* x      = d_in[0];
    const void* qkv_w  = d_in[1];
    const void* q_bias = d_in[2];
    const void* v_bias = d_in[3];
    const void* lscale = d_in[4];
    const void* cpb_w1 = d_in[5];
    const void* cpb_b1 = d_in[6];
    const void* cpb_w2 = d_in[7];
    const void* proj_w = d_in[8];
    const void* proj_b = d_in[9];
    const void* rct    = d_in[10];
    const int*  rpi    = (const int*)d_in[11];

    char* ws = (char*)d_ws;
    ushort_t* qkv_ws  = (ushort_t*)ws;                          // 3*WSQ bf16 = 150,994,944 B
    float*    bt      = (float*)(ws + 150994944L);              // 961*12 f32
    float*    rpb     = (float*)(ws + 151060480L);              // 12*65536 f32 = 3,145,728 B
    int*      flag    = (int*)(ws + 154206208L);

    detect_kernel<<<1, 64, 0, stream>>>((const ushort_t*)x, flag);
    cpb_kernel<<<961, 512, 0, stream>>>(rct, cpb_w1, cpb_b1, cpb_w2, flag, bt);
    rpb_kernel<<<3072, 256, 0, stream>>>(rpi, bt, lscale, flag, rpb);
    gemm_bt<0><<<4608, 256, 0, stream>>>(x, qkv_w, q_bias, v_bias, qkv_ws, flag);
    attn_kernel<<<3072, 256, 0, stream>>>(qkv_ws, lscale, rpb, flag);
    gemm_bt<1><<<1536, 256, 0, stream>>>(qkv_ws, proj_w, proj_b, nullptr, d_out, flag);
}

// Round 7
// 468.667 us; speedup vs baseline: 1.3260x; 1.3260x over previous
//
#include <hip/hip_runtime.h>

typedef unsigned int uint;
typedef unsigned short ushort_t;
typedef ushort_t ushort8 __attribute__((ext_vector_type(8)));
typedef ushort_t ushort4v __attribute__((ext_vector_type(4)));
typedef short short8 __attribute__((ext_vector_type(8)));
typedef float floatx4 __attribute__((ext_vector_type(4)));
typedef uint uint2v __attribute__((ext_vector_type(2)));
typedef uint uint4v __attribute__((ext_vector_type(4)));

#define WSQ 25165824L   // elements per q/k/v tensor: 256*12*256*32
#define NH  12
#define NT  256
#define HD  32

__device__ __forceinline__ float bf2f(ushort_t u) {
    uint x = ((uint)u) << 16;
    return __builtin_bit_cast(float, x);
}
__device__ __forceinline__ ushort_t f2bf(float f) {
    uint u = __builtin_bit_cast(uint, f);
    uint lsb = (u >> 16) & 1u;
    return (ushort_t)((u + 0x7FFFu + lsb) >> 16);
}
// packed f32x2 -> bf16x2 (RNE in HW), 1 inst instead of ~8
__device__ __forceinline__ uint cvt_pk_bf16(float lo, float hi) {
    uint r;
    asm("v_cvt_pk_bf16_f32 %0, %1, %2" : "=v"(r) : "v"(lo), "v"(hi));
    return r;
}
__device__ __forceinline__ float exp2_fast(float x) {
    float r;
    asm("v_exp_f32 %0, %1" : "=v"(r) : "v"(x));
    return r;
}
// gfx950 cross-lane row swaps via verified builtins (return {new_a, new_b}).
__device__ __forceinline__ void permlane32_swap(uint& a, uint& b) {
    uint2v r = __builtin_amdgcn_permlane32_swap(a, b, false, false);
    a = r[0]; b = r[1];
}
__device__ __forceinline__ void permlane16_swap(uint& a, uint& b) {
    uint2v r = __builtin_amdgcn_permlane16_swap(a, b, false, false);
    a = r[0]; b = r[1];
}
__device__ __forceinline__ float ld1(const void* p, long i, int f) {
    return f ? ((const float*)p)[i] : bf2f(((const ushort_t*)p)[i]);
}
// async global->LDS, 16 bytes per lane; dest = wave-uniform base + lane*16
__device__ __forceinline__ void gld_lds16(const ushort_t* g, ushort_t* l) {
    __builtin_amdgcn_global_load_lds(
        (const __attribute__((address_space(1))) void*)g,
        (__attribute__((address_space(3))) void*)l, 16, 0, 0);
}

// ---------------- dtype detection: 1 wave ----------------
__global__ void detect_kernel(const ushort_t* __restrict__ x, int* __restrict__ flag) {
    int t = threadIdx.x;                 // 64 threads
    uint u = x[2 * t];                   // low half if f32, element 2t if bf16
    int e = (u >> 7) & 0xFF;
    int weird = (e > 147 || e < 107) ? 1 : 0;   // |exp-127| > 20
    unsigned long long b = __ballot(weird);
    if (t == 0) *flag = (__popcll(b) > 19) ? 1 : 0;   // >30% weird -> f32
}

// ---------------- convert to bf16 (or copy) ----------------
__global__ __launch_bounds__(256) void cvt_kernel(
    const void* __restrict__ src, ushort_t* __restrict__ dst,
    const int* __restrict__ fl, long n8)
{
    long i = (long)blockIdx.x * 256 + threadIdx.x;
    if (i >= n8) return;
    if (*fl) {
        const floatx4* s = (const floatx4*)((const float*)src + i * 8);
        floatx4 a = s[0], b = s[1];
        uint4v u;
        u[0] = cvt_pk_bf16(a[0], a[1]); u[1] = cvt_pk_bf16(a[2], a[3]);
        u[2] = cvt_pk_bf16(b[0], b[1]); u[3] = cvt_pk_bf16(b[2], b[3]);
        *(uint4v*)(dst + i * 8) = u;
    } else {
        *(ushort8*)(dst + i * 8) = *(const ushort8*)((const ushort_t*)src + i * 8);
    }
}

// ---------------- CPB MLP: 2 -> 512 -> 12 ----------------
__global__ __launch_bounds__(512) void cpb_kernel(
    const void* __restrict__ tab, const void* __restrict__ w1,
    const void* __restrict__ b1, const void* __restrict__ w2,
    const int* __restrict__ fl, float* __restrict__ bt)
{
    __shared__ float hid[512];
    const int f = *fl;
    int p = blockIdx.x, j = threadIdx.x;
    float c0 = ld1(tab, p * 2 + 0, f);
    float c1 = ld1(tab, p * 2 + 1, f);
    float v = ld1(w1, j * 2 + 0, f) * c0 + ld1(w1, j * 2 + 1, f) * c1 + ld1(b1, j, f);
    hid[j] = fmaxf(v, 0.0f);
    __syncthreads();
    if (j < NH) {
        float s = 0.0f;
        for (int i = 0; i < 512; ++i) s += hid[i] * ld1(w2, (long)j * 512 + i, f);
        bt[p * NH + j] = s;
    }
}

// ---------------- rpb gather + 16*sigmoid, log2 domain, bound-shifted ----------------
// Stores rpb' = 16*sigmoid(x)*log2e - B_h, with B_h = min(scale_h,40)*1.02 + 23.1.
// For scale<=40 the attn fast path uses exp2(S*scale + rpb') directly (no max pass).
__global__ __launch_bounds__(256) void rpb_kernel(
    const int* __restrict__ rpi, const float* __restrict__ bt,
    const void* __restrict__ ls, const int* __restrict__ fl,
    float* __restrict__ rpb)
{
    int idx = blockIdx.x * 256 + threadIdx.x;      // 12*65536 total
    int h = idx >> 16, ij = idx & 65535;
    float x = bt[rpi[ij] * NH + h];
    float scale = __expf(fminf(ld1(ls, h, *fl), 4.6051702f)) * 1.44269504f;
    float bound = fminf(scale, 40.0f) * 1.02f + 23.1f;
    rpb[idx] = 1.44269504f * 16.0f / (1.0f + __expf(-x)) - bound;
}

// ---------------- GEMM C = A[M,384] @ W[N,384]^T + bias (all bf16 in) ----------------
// MODE 0: qkv projection: A = xb, scatter-store bf16 [which][B,H,N,32]
// MODE 1: out projection: A = attn overlay in qkv q-region, store dual to d_out
// Staging via global_load_lds width=16 (no VGPR round-trip). LDS is LINEAR
// [128][64]; bank conflicts avoided by XOR-swizzling the SOURCE column at stage
// time and the column at read time (Guideline 21): LDS[r][c] = G[r][c^((r&7)*8)].
// 1D grid + bijective XCD-chunk swizzle (each XCD owns a contiguous m-range).
template <int MODE>
__global__ __launch_bounds__(256) void gemm_bt(
    const ushort_t* __restrict__ A, const ushort_t* __restrict__ Bw,
    const void* __restrict__ bias0, const void* __restrict__ bias2,
    void* __restrict__ Cout, const int* __restrict__ fl)
{
    const int K = 384;
    const int NBX = (MODE == 0) ? 9 : 3;        // n-blocks
    const int CHUNK = NBX * 512 / 8;            // blocks per XCD (576 / 192, both exact)
    __shared__ __attribute__((aligned(16))) ushort_t As[128 * 64];
    __shared__ __attribute__((aligned(16))) ushort_t Bs[128 * 64];
    const int f = *fl;
    const int tid = threadIdx.x;
    const int w = tid >> 6, lane = tid & 63, l15 = lane & 15, quad = lane >> 4;
    const int bid = blockIdx.x;
    const int wg = (bid & 7) * CHUNK + (bid >> 3);
    const int m0 = (wg / NBX) * 128, n0 = (wg % NBX) * 128;
    const int rw = (w >> 1) * 64, cw = (w & 1) * 64;

    // staging geometry: chunk c (0..15) = rows 8c..8c+7; wave w stages c = w*4+j.
    // lane l: row = 8c + (l>>3); LDS col (l&7)*8 (linear); source col swizzled:
    const int lrow = lane >> 3;
    const int lcs  = ((lane & 7) ^ lrow) * 8;   // swizzled source col (elements)
    const int sw   = (l15 & 7) * 8;             // read-side XOR (row&7 == l15&7)

    floatx4 acc[4][4] = {};

    for (int kt = 0; kt < K; kt += 64) {
        if (kt) __syncthreads();                // all reads of prev tile done
        #pragma unroll
        for (int j = 0; j < 4; ++j) {
            const int c = w * 4 + j;
            const int row = c * 8 + lrow;       // 0..127
            long ga;
            if (MODE == 0) {
                ga = (long)(m0 + row) * K + kt + lcs;
            } else {
                int m = m0 + row, kc = kt + lcs;
                ga = ((long)(m >> 8) * 12 + (kc >> 5)) * 8192 + (m & 255) * 32 + (kc & 31);
            }
            gld_lds16(&A[ga], &As[c * 512]);
            long gb = (long)(n0 + row) * K + kt + lcs;
            gld_lds16(&Bw[gb], &Bs[c * 512]);
        }
        __syncthreads();                        // compiler drains vmcnt before barrier
        #pragma unroll
        for (int ks = 0; ks < 64; ks += 32) {
            short8 af[4], bfr[4];
            const int col = (ks + quad * 8) ^ sw;
            #pragma unroll
            for (int mt = 0; mt < 4; ++mt)
                af[mt] = *(short8*)&As[(rw + mt * 16 + l15) * 64 + col];
            #pragma unroll
            for (int nt = 0; nt < 4; ++nt)
                bfr[nt] = *(short8*)&Bs[(cw + nt * 16 + l15) * 64 + col];
            #pragma unroll
            for (int mt = 0; mt < 4; ++mt)
                #pragma unroll
                for (int nt = 0; nt < 4; ++nt)
                    acc[mt][nt] = __builtin_amdgcn_mfma_f32_16x16x32_bf16(
                        af[mt], bfr[nt], acc[mt][nt], 0, 0, 0);
        }
    }

    for (int mt = 0; mt < 4; ++mt) {
        for (int nt = 0; nt < 4; ++nt) {
            int c = n0 + cw + nt * 16 + l15;
            if (MODE == 0) {
                int which = c / 384, cc = c % 384;
                float bias = (which == 0) ? ld1(bias0, cc, f)
                           : (which == 2) ? ld1(bias2, cc, f) : 0.0f;
                int hh = cc >> 5, dd = cc & 31;
                for (int r = 0; r < 4; ++r) {
                    int m = m0 + rw + mt * 16 + quad * 4 + r;
                    int b = m >> 8, ntok = m & 255;
                    long dst = (long)which * WSQ +
                               (((long)(b * NH + hh) * NT + ntok) * HD + dd);
                    ((ushort_t*)Cout)[dst] = f2bf(acc[mt][nt][r] + bias);
                }
            } else {
                float bias = ld1(bias0, c, f);
                for (int r = 0; r < 4; ++r) {
                    int m = m0 + rw + mt * 16 + quad * 4 + r;
                    float v = acc[mt][nt][r] + bias;
                    long o = (long)m * 384 + c;
                    if (f) ((float*)Cout)[o] = v;
                    else   ((ushort_t*)Cout)[o] = f2bf(v);
                }
            }
        }
    }
}

// ---------------- fused window attention: one block per (b,h), 256 thr / 4 waves ----------------
// Single-pass softmax: rpb pre-shifted by -B_h, p = exp2(fmaf(S,scale,rpb')) straight
// off the S^T MFMA. P never touches LDS (cvt_pk + permlane quad-transpose).
// LDS = ks + vts (37,376 B) -> 4 blocks/CU x 4 waves. setprio(1) around MFMA
// clusters (barrier-free phase-staggered waves -> m191 regime).
__global__ __launch_bounds__(256, 4) void attn_kernel(
    ushort_t* __restrict__ qkv, const void* __restrict__ ls,
    const float* __restrict__ rpb, const int* __restrict__ fl)
{
    __shared__ __attribute__((aligned(16))) ushort_t ks[256 * 40];    // 20480 B
    __shared__ __attribute__((aligned(16))) ushort_t vts[32 * 264];   // 16896 B

    const int f = *fl;
    // bijective: 3072 = 8 XCD x (12 h x 32 windows); same-h blocks contiguous per XCD
    const int bid = blockIdx.x;
    const int xcd = bid & 7, local = bid >> 3;
    const int h = local >> 5, bwin = (xcd << 5) + (local & 31);
    const int bh = bwin * NH + h;
    ushort_t* qp = qkv + (long)bh * NT * HD;
    const ushort_t* kp = qp + WSQ;
    const ushort_t* vp = qp + 2 * WSQ;
    const int tid = threadIdx.x;
    // logit scale, log2 domain (matches pre-scaled rpb)
    const float scale = __expf(fminf(ld1(ls, h, f), 4.6051702f)) * 1.44269504f;

    // ---- stage K (L2-normalized) and V^T: one token per thread ----
    {
        const int t = tid;
        ushort8 kv[4];
        #pragma unroll
        for (int i = 0; i < 4; ++i) kv[i] = *(const ushort8*)&kp[t * HD + i * 8];
        float fv[32]; float ss = 0.0f;
        #pragma unroll
        for (int i = 0; i < 4; ++i)
            #pragma unroll
            for (int j = 0; j < 8; ++j) {
                float v = bf2f(kv[i][j]); fv[i * 8 + j] = v; ss += v * v;
            }
        float rn = 1.0f / fmaxf(sqrtf(ss), 1e-12f);
        #pragma unroll
        for (int i = 0; i < 4; ++i) {
            uint4v o;
            #pragma unroll
            for (int j = 0; j < 4; ++j)
                o[j] = cvt_pk_bf16(fv[i * 8 + 2 * j] * rn, fv[i * 8 + 2 * j + 1] * rn);
            *(uint4v*)&ks[t * 40 + i * 8] = o;
        }
        ushort8 vv[4];
        #pragma unroll
        for (int i = 0; i < 4; ++i) vv[i] = *(const ushort8*)&vp[t * HD + i * 8];
        #pragma unroll
        for (int i = 0; i < 4; ++i)
            #pragma unroll
            for (int j = 0; j < 8; ++j) vts[(i * 8 + j) * 264 + t] = vv[i][j];
    }
    __syncthreads();

    const int w = tid >> 6, lane = tid & 63, l15 = lane & 15, quad = lane >> 4;

    if (scale <= 40.0f) {
      // ================= fast path: bound-shifted single-pass softmax =================
      for (int c = 0; c < 4; ++c) {
        const int mloc = w * 64 + c * 16;

        // q fragment: lane holds q[mloc+l15][quad*8..+8]; normalize via shfl
        ushort8 qv = *(const ushort8*)&qp[(mloc + l15) * HD + quad * 8];
        float qf[8]; float ss = 0.0f;
        #pragma unroll
        for (int j = 0; j < 8; ++j) { qf[j] = bf2f(qv[j]); ss += qf[j] * qf[j]; }
        ss += __shfl_xor(ss, 16, 64);
        ss += __shfl_xor(ss, 32, 64);
        float rn = 1.0f / fmaxf(sqrtf(ss), 1e-12f);
        uint4v qa;
        #pragma unroll
        for (int j = 0; j < 4; ++j)
            qa[j] = cvt_pk_bf16(qf[2 * j] * rn, qf[2 * j + 1] * rn);
        short8 aq = __builtin_bit_cast(short8, qa);

        // S^T strip: MFMA(A=k, B=q) -> D[key][token]; lane: token=l15, keys=t*16+quad*4+r
        floatx4 accS[16];
        __builtin_amdgcn_s_setprio(1);
        #pragma unroll
        for (int t = 0; t < 16; ++t) {
            short8 bk = *(short8*)&ks[(t * 16 + l15) * 40 + quad * 8];
            floatx4 z = {};
            accS[t] = __builtin_amdgcn_mfma_f32_16x16x32_bf16(bk, aq, z, 0, 0, 0);
        }
        __builtin_amdgcn_s_setprio(0);

        const float* rp = rpb + ((long)h * NT + mloc + l15) * NT;
        const floatx4* rp4 = (const floatx4*)rp;   // strip t, quad -> rp4[t*4+quad]

        // 8 PV phases: fused exp2(fmaf(S,scale,rpb')) + pack + permlane + 2 MFMA.
        float s4[4] = {0.f, 0.f, 0.f, 0.f};
        floatx4 accO[2] = {};
        floatx4 rb0 = rp4[quad], rb1 = rp4[4 + quad];
        #pragma unroll
        for (int kk = 0; kk < 8; ++kk) {
            short8 vf0 = *(short8*)&vts[l15 * 264 + kk * 32 + quad * 8];
            short8 vf1 = *(short8*)&vts[(16 + l15) * 264 + kk * 32 + quad * 8];
            floatx4 nb0 = rb0, nb1 = rb1;
            if (kk < 7) { nb0 = rp4[8 * (kk + 1) + quad]; nb1 = rp4[8 * (kk + 1) + 4 + quad]; }
            const int t0 = 2 * kk, t1 = 2 * kk + 1;
            float a0 = exp2_fast(fmaf(accS[t0][0], scale, rb0[0]));
            float a1 = exp2_fast(fmaf(accS[t0][1], scale, rb0[1]));
            float a2 = exp2_fast(fmaf(accS[t0][2], scale, rb0[2]));
            float a3 = exp2_fast(fmaf(accS[t0][3], scale, rb0[3]));
            float e0 = exp2_fast(fmaf(accS[t1][0], scale, rb1[0]));
            float e1 = exp2_fast(fmaf(accS[t1][1], scale, rb1[1]));
            float e2 = exp2_fast(fmaf(accS[t1][2], scale, rb1[2]));
            float e3 = exp2_fast(fmaf(accS[t1][3], scale, rb1[3]));
            s4[0] += a0 + e0; s4[1] += a1 + e1;
            s4[2] += a2 + e2; s4[3] += a3 + e3;
            uint A0 = cvt_pk_bf16(a0, a1), A1 = cvt_pk_bf16(a2, a3);
            uint B0 = cvt_pk_bf16(e0, e1), B1 = cvt_pk_bf16(e2, e3);
            permlane32_swap(A0, B0); permlane16_swap(A0, B0);
            permlane32_swap(A1, B1); permlane16_swap(A1, B1);
            uint4v pw; pw[0] = A0; pw[1] = A1; pw[2] = B0; pw[3] = B1;
            short8 pf = __builtin_bit_cast(short8, pw);
            __builtin_amdgcn_s_setprio(1);
            accO[0] = __builtin_amdgcn_mfma_f32_16x16x32_bf16(pf, vf0, accO[0], 0, 0, 0);
            accO[1] = __builtin_amdgcn_mfma_f32_16x16x32_bf16(pf, vf1, accO[1], 0, 0, 0);
            __builtin_amdgcn_s_setprio(0);
            rb0 = nb0; rb1 = nb1;
        }

        float rsum = (s4[0] + s4[1]) + (s4[2] + s4[3]);
        rsum += __shfl_xor(rsum, 16, 64);
        rsum += __shfl_xor(rsum, 32, 64);
        float rinv = 1.0f / rsum;
        float ri[4];
        #pragma unroll
        for (int r = 0; r < 4; ++r) ri[r] = __shfl(rinv, quad * 4 + r, 64);

        // epilogue: D[token=quad*4+r][d=tn*16+l15], fold 1/rsum here
        #pragma unroll
        for (int tn = 0; tn < 2; ++tn)
            #pragma unroll
            for (int r = 0; r < 4; r += 2) {
                uint pk = cvt_pk_bf16(accO[tn][r] * ri[r], accO[tn][r + 1] * ri[r + 1]);
                int n = mloc + quad * 4 + r;
                qp[n * HD + tn * 16 + l15] = (ushort_t)pk;
                qp[(n + 1) * HD + tn * 16 + l15] = (ushort_t)(pk >> 16);
            }
      }
    } else {
      // ============ exact-max fallback (scale>40; uniform rpb shift cancels) ============
      for (int c = 0; c < 4; ++c) {
        const int mloc = w * 64 + c * 16;

        ushort8 qv = *(const ushort8*)&qp[(mloc + l15) * HD + quad * 8];
        float qf[8]; float ss = 0.0f;
        #pragma unroll
        for (int j = 0; j < 8; ++j) { qf[j] = bf2f(qv[j]); ss += qf[j] * qf[j]; }
        ss += __shfl_xor(ss, 16, 64);
        ss += __shfl_xor(ss, 32, 64);
        float rn = 1.0f / fmaxf(sqrtf(ss), 1e-12f);
        uint4v qa;
        #pragma unroll
        for (int j = 0; j < 4; ++j)
            qa[j] = cvt_pk_bf16(qf[2 * j] * rn, qf[2 * j + 1] * rn);
        short8 aq = __builtin_bit_cast(short8, qa);

        floatx4 accS[16];
        #pragma unroll
        for (int t = 0; t < 16; ++t) {
            short8 bk = *(short8*)&ks[(t * 16 + l15) * 40 + quad * 8];
            floatx4 z = {};
            accS[t] = __builtin_amdgcn_mfma_f32_16x16x32_bf16(bk, aq, z, 0, 0, 0);
        }

        const float* rp = rpb + ((long)h * NT + mloc + l15) * NT;
        float m4[4] = {-3e38f, -3e38f, -3e38f, -3e38f};
        #pragma unroll
        for (int t = 0; t < 16; ++t) {
            floatx4 rb = *(const floatx4*)&rp[t * 16 + quad * 4];
            float v0 = fmaf(accS[t][0], scale, rb[0]);
            float v1 = fmaf(accS[t][1], scale, rb[1]);
            float v2 = fmaf(accS[t][2], scale, rb[2]);
            float v3 = fmaf(accS[t][3], scale, rb[3]);
            accS[t][0] = v0; accS[t][1] = v1; accS[t][2] = v2; accS[t][3] = v3;
            m4[t & 3] = fmaxf(m4[t & 3], fmaxf(fmaxf(v0, v1), fmaxf(v2, v3)));
        }
        float rmax = fmaxf(fmaxf(m4[0], m4[1]), fmaxf(m4[2], m4[3]));
        rmax = fmaxf(rmax, __shfl_xor(rmax, 16, 64));
        rmax = fmaxf(rmax, __shfl_xor(rmax, 32, 64));

        float s4[4] = {0.f, 0.f, 0.f, 0.f};
        floatx4 accO[2] = {};
        #pragma unroll
        for (int kk = 0; kk < 8; ++kk) {
            short8 vf0 = *(short8*)&vts[l15 * 264 + kk * 32 + quad * 8];
            short8 vf1 = *(short8*)&vts[(16 + l15) * 264 + kk * 32 + quad * 8];
            const int t0 = 2 * kk, t1 = 2 * kk + 1;
            float a0 = exp2_fast(accS[t0][0] - rmax);
            float a1 = exp2_fast(accS[t0][1] - rmax);
            float a2 = exp2_fast(accS[t0][2] - rmax);
            float a3 = exp2_fast(accS[t0][3] - rmax);
            float e0 = exp2_fast(accS[t1][0] - rmax);
            float e1 = exp2_fast(accS[t1][1] - rmax);
            float e2 = exp2_fast(accS[t1][2] - rmax);
            float e3 = exp2_fast(accS[t1][3] - rmax);
            s4[0] += a0 + e0; s4[1] += a1 + e1;
            s4[2] += a2 + e2; s4[3] += a3 + e3;
            uint A0 = cvt_pk_bf16(a0, a1), A1 = cvt_pk_bf16(a2, a3);
            uint B0 = cvt_pk_bf16(e0, e1), B1 = cvt_pk_bf16(e2, e3);
            permlane32_swap(A0, B0); permlane16_swap(A0, B0);
            permlane32_swap(A1, B1); permlane16_swap(A1, B1);
            uint4v pw; pw[0] = A0; pw[1] = A1; pw[2] = B0; pw[3] = B1;
            short8 pf = __builtin_bit_cast(short8, pw);
            accO[0] = __builtin_amdgcn_mfma_f32_16x16x32_bf16(pf, vf0, accO[0], 0, 0, 0);
            accO[1] = __builtin_amdgcn_mfma_f32_16x16x32_bf16(pf, vf1, accO[1], 0, 0, 0);
        }

        float rsum = (s4[0] + s4[1]) + (s4[2] + s4[3]);
        rsum += __shfl_xor(rsum, 16, 64);
        rsum += __shfl_xor(rsum, 32, 64);
        float rinv = 1.0f / rsum;
        float ri[4];
        #pragma unroll
        for (int r = 0; r < 4; ++r) ri[r] = __shfl(rinv, quad * 4 + r, 64);

        #pragma unroll
        for (int tn = 0; tn < 2; ++tn)
            #pragma unroll
            for (int r = 0; r < 4; r += 2) {
                uint pk = cvt_pk_bf16(accO[tn][r] * ri[r], accO[tn][r + 1] * ri[r + 1]);
                int n = mloc + quad * 4 + r;
                qp[n * HD + tn * 16 + l15] = (ushort_t)pk;
                qp[(n + 1) * HD + tn * 16 + l15] = (ushort_t)(pk >> 16);
            }
      }
    }
}

extern "C" void kernel_launch(void* const* d_in, const int* in_sizes, int n_in,
                              void* d_out, int out_size, void* d_ws, size_t ws_size,
                              hipStream_t stream)
{
    const void* x      = d_in[0];
    const void* qkv_w  = d_in[1];
    const void* q_bias = d_in[2];
    const void* v_bias = d_in[3];
    const void* lscale = d_in[4];
    const void* cpb_w1 = d_in[5];
    const void* cpb_b1 = d_in[6];
    const void* cpb_w2 = d_in[7];
    const void* proj_w = d_in[8];
    const void* proj_b = d_in[9];
    const void* rct    = d_in[10];
    const int*  rpi    = (const int*)d_in[11];

    char* ws = (char*)d_ws;
    ushort_t* qkv_ws  = (ushort_t*)ws;                          // 3*WSQ bf16 = 150,994,944 B
    float*    bt      = (float*)(ws + 150994944L);              // 961*12 f32
    float*    rpb     = (float*)(ws + 151060480L);              // 12*65536 f32 = 3,145,728 B
    int*      flag    = (int*)(ws + 154206208L);
    ushort_t* wqkv_b  = (ushort_t*)(ws + 154206464L);           // 1152*384 bf16 = 884,736 B
    ushort_t* wproj_b = (ushort_t*)(ws + 155091200L);           // 384*384 bf16 = 294,912 B
    ushort_t* xb      = (ushort_t*)d_out;                       // x in bf16 (50.3 MB scratch,
                                                                // consumed before final store)

    detect_kernel<<<1, 64, 0, stream>>>((const ushort_t*)x, flag);
    cvt_kernel<<<12288, 256, 0, stream>>>(x, xb, flag, 3145728L);      // x: 25,165,824 el
    cvt_kernel<<<216, 256, 0, stream>>>(qkv_w, wqkv_b, flag, 55296L);  // 442,368 el
    cvt_kernel<<<72, 256, 0, stream>>>(proj_w, wproj_b, flag, 18432L); // 147,456 el
    cpb_kernel<<<961, 512, 0, stream>>>(rct, cpb_w1, cpb_b1, cpb_w2, flag, bt);
    rpb_kernel<<<3072, 256, 0, stream>>>(rpi, bt, lscale, flag, rpb);
    gemm_bt<0><<<4608, 256, 0, stream>>>(xb, wqkv_b, q_bias, v_bias, qkv_ws, flag);
    attn_kernel<<<3072, 256, 0, stream>>>(qkv_ws, lscale, rpb, flag);
    gemm_bt<1><<<1536, 256, 0, stream>>>(qkv_ws, wproj_b, proj_b, nullptr, d_out, flag);
}

// Round 8
// 458.291 us; speedup vs baseline: 1.3561x; 1.0226x over previous
//
#include <hip/hip_runtime.h>

typedef unsigned int uint;
typedef unsigned short ushort_t;
typedef ushort_t ushort8 __attribute__((ext_vector_type(8)));
typedef ushort_t ushort4v __attribute__((ext_vector_type(4)));
typedef short short8 __attribute__((ext_vector_type(8)));
typedef float floatx4 __attribute__((ext_vector_type(4)));
typedef uint uint2v __attribute__((ext_vector_type(2)));
typedef uint uint4v __attribute__((ext_vector_type(4)));

#define WSQ 25165824L   // elements per q/k/v tensor: 256*12*256*32
#define NH  12
#define NT  256
#define HD  32

__device__ __forceinline__ float bf2f(ushort_t u) {
    uint x = ((uint)u) << 16;
    return __builtin_bit_cast(float, x);
}
__device__ __forceinline__ ushort_t f2bf(float f) {
    uint u = __builtin_bit_cast(uint, f);
    uint lsb = (u >> 16) & 1u;
    return (ushort_t)((u + 0x7FFFu + lsb) >> 16);
}
// packed f32x2 -> bf16x2 (RNE in HW), 1 inst instead of ~8
__device__ __forceinline__ uint cvt_pk_bf16(float lo, float hi) {
    uint r;
    asm("v_cvt_pk_bf16_f32 %0, %1, %2" : "=v"(r) : "v"(lo), "v"(hi));
    return r;
}
__device__ __forceinline__ float exp2_fast(float x) {
    float r;
    asm("v_exp_f32 %0, %1" : "=v"(r) : "v"(x));
    return r;
}
// gfx950 cross-lane row swaps via verified builtins (return {new_a, new_b}).
__device__ __forceinline__ void permlane32_swap(uint& a, uint& b) {
    uint2v r = __builtin_amdgcn_permlane32_swap(a, b, false, false);
    a = r[0]; b = r[1];
}
__device__ __forceinline__ void permlane16_swap(uint& a, uint& b) {
    uint2v r = __builtin_amdgcn_permlane16_swap(a, b, false, false);
    a = r[0]; b = r[1];
}
__device__ __forceinline__ float ld1(const void* p, long i, int f) {
    return f ? ((const float*)p)[i] : bf2f(((const ushort_t*)p)[i]);
}
// async global->LDS, 16 bytes per lane; dest = wave-uniform base + lane*16
__device__ __forceinline__ void gld_lds16(const ushort_t* g, ushort_t* l) {
    __builtin_amdgcn_global_load_lds(
        (const __attribute__((address_space(1))) void*)g,
        (__attribute__((address_space(3))) void*)l, 16, 0, 0);
}

// ---------------- dtype detection: 1 wave ----------------
__global__ void detect_kernel(const ushort_t* __restrict__ x, int* __restrict__ flag) {
    int t = threadIdx.x;                 // 64 threads
    uint u = x[2 * t];                   // low half if f32, element 2t if bf16
    int e = (u >> 7) & 0xFF;
    int weird = (e > 147 || e < 107) ? 1 : 0;   // |exp-127| > 20
    unsigned long long b = __ballot(weird);
    if (t == 0) *flag = (__popcll(b) > 19) ? 1 : 0;   // >30% weird -> f32
}

// ---------------- convert to bf16 (or copy) ----------------
__global__ __launch_bounds__(256) void cvt_kernel(
    const void* __restrict__ src, ushort_t* __restrict__ dst,
    const int* __restrict__ fl, long n8)
{
    long i = (long)blockIdx.x * 256 + threadIdx.x;
    if (i >= n8) return;
    if (*fl) {
        const floatx4* s = (const floatx4*)((const float*)src + i * 8);
        floatx4 a = s[0], b = s[1];
        uint4v u;
        u[0] = cvt_pk_bf16(a[0], a[1]); u[1] = cvt_pk_bf16(a[2], a[3]);
        u[2] = cvt_pk_bf16(b[0], b[1]); u[3] = cvt_pk_bf16(b[2], b[3]);
        *(uint4v*)(dst + i * 8) = u;
    } else {
        *(ushort8*)(dst + i * 8) = *(const ushort8*)((const ushort_t*)src + i * 8);
    }
}

// ---------------- CPB MLP: 2 -> 512 -> 12 ----------------
__global__ __launch_bounds__(512) void cpb_kernel(
    const void* __restrict__ tab, const void* __restrict__ w1,
    const void* __restrict__ b1, const void* __restrict__ w2,
    const int* __restrict__ fl, float* __restrict__ bt)
{
    __shared__ float hid[512];
    const int f = *fl;
    int p = blockIdx.x, j = threadIdx.x;
    float c0 = ld1(tab, p * 2 + 0, f);
    float c1 = ld1(tab, p * 2 + 1, f);
    float v = ld1(w1, j * 2 + 0, f) * c0 + ld1(w1, j * 2 + 1, f) * c1 + ld1(b1, j, f);
    hid[j] = fmaxf(v, 0.0f);
    __syncthreads();
    if (j < NH) {
        float s = 0.0f;
        for (int i = 0; i < 512; ++i) s += hid[i] * ld1(w2, (long)j * 512 + i, f);
        bt[p * NH + j] = s;
    }
}

// ---------------- rpb gather + 16*sigmoid, log2 domain, bound-shifted ----------------
// Stores rpb' = 16*sigmoid(x)*log2e - B_h, with B_h = min(scale_h,40)*1.02 + 23.1.
// For scale<=40 the attn fast path uses exp2(S*scale + rpb') directly (no max pass).
__global__ __launch_bounds__(256) void rpb_kernel(
    const int* __restrict__ rpi, const float* __restrict__ bt,
    const void* __restrict__ ls, const int* __restrict__ fl,
    float* __restrict__ rpb)
{
    int idx = blockIdx.x * 256 + threadIdx.x;      // 12*65536 total
    int h = idx >> 16, ij = idx & 65535;
    float x = bt[rpi[ij] * NH + h];
    float scale = __expf(fminf(ld1(ls, h, *fl), 4.6051702f)) * 1.44269504f;
    float bound = fminf(scale, 40.0f) * 1.02f + 23.1f;
    rpb[idx] = 1.44269504f * 16.0f / (1.0f + __expf(-x)) - bound;
}

// ---------------- GEMM C = A[M,384] @ W[N,384]^T + bias (all bf16 in) ----------------
// MODE 0: qkv projection: A = xb, scatter-store bf16 [which][B,H,N,32]
// MODE 1: out projection: A = attn overlay in qkv q-region, store dual to d_out
// Staging via global_load_lds width=16 (no VGPR round-trip). LDS is LINEAR
// [128][64]; bank conflicts avoided by XOR-swizzling the SOURCE column at stage
// time and the column at read time (Guideline 21): LDS[r][c] = G[r][c^((r&7)*8)].
// 1D grid + bijective XCD-chunk swizzle (each XCD owns a contiguous m-range).
template <int MODE>
__global__ __launch_bounds__(256) void gemm_bt(
    const ushort_t* __restrict__ A, const ushort_t* __restrict__ Bw,
    const void* __restrict__ bias0, const void* __restrict__ bias2,
    void* __restrict__ Cout, const int* __restrict__ fl)
{
    const int K = 384;
    const int NBX = (MODE == 0) ? 9 : 3;        // n-blocks
    const int CHUNK = NBX * 512 / 8;            // blocks per XCD (576 / 192, both exact)
    __shared__ __attribute__((aligned(16))) ushort_t As[128 * 64];
    __shared__ __attribute__((aligned(16))) ushort_t Bs[128 * 64];
    const int f = *fl;
    const int tid = threadIdx.x;
    const int w = tid >> 6, lane = tid & 63, l15 = lane & 15, quad = lane >> 4;
    const int bid = blockIdx.x;
    const int wg = (bid & 7) * CHUNK + (bid >> 3);
    const int m0 = (wg / NBX) * 128, n0 = (wg % NBX) * 128;
    const int rw = (w >> 1) * 64, cw = (w & 1) * 64;

    // staging geometry: chunk c (0..15) = rows 8c..8c+7; wave w stages c = w*4+j.
    // lane l: row = 8c + (l>>3); LDS col (l&7)*8 (linear); source col swizzled:
    const int lrow = lane >> 3;
    const int lcs  = ((lane & 7) ^ lrow) * 8;   // swizzled source col (elements)
    const int sw   = (l15 & 7) * 8;             // read-side XOR (row&7 == l15&7)

    floatx4 acc[4][4] = {};

    for (int kt = 0; kt < K; kt += 64) {
        if (kt) __syncthreads();                // all reads of prev tile done
        #pragma unroll
        for (int j = 0; j < 4; ++j) {
            const int c = w * 4 + j;
            const int row = c * 8 + lrow;       // 0..127
            long ga;
            if (MODE == 0) {
                ga = (long)(m0 + row) * K + kt + lcs;
            } else {
                int m = m0 + row, kc = kt + lcs;
                ga = ((long)(m >> 8) * 12 + (kc >> 5)) * 8192 + (m & 255) * 32 + (kc & 31);
            }
            gld_lds16(&A[ga], &As[c * 512]);
            long gb = (long)(n0 + row) * K + kt + lcs;
            gld_lds16(&Bw[gb], &Bs[c * 512]);
        }
        __syncthreads();                        // compiler drains vmcnt before barrier
        #pragma unroll
        for (int ks = 0; ks < 64; ks += 32) {
            short8 af[4], bfr[4];
            const int col = (ks + quad * 8) ^ sw;
            #pragma unroll
            for (int mt = 0; mt < 4; ++mt)
                af[mt] = *(short8*)&As[(rw + mt * 16 + l15) * 64 + col];
            #pragma unroll
            for (int nt = 0; nt < 4; ++nt)
                bfr[nt] = *(short8*)&Bs[(cw + nt * 16 + l15) * 64 + col];
            #pragma unroll
            for (int mt = 0; mt < 4; ++mt)
                #pragma unroll
                for (int nt = 0; nt < 4; ++nt)
                    acc[mt][nt] = __builtin_amdgcn_mfma_f32_16x16x32_bf16(
                        af[mt], bfr[nt], acc[mt][nt], 0, 0, 0);
        }
    }

    for (int mt = 0; mt < 4; ++mt) {
        for (int nt = 0; nt < 4; ++nt) {
            int c = n0 + cw + nt * 16 + l15;
            if (MODE == 0) {
                int which = c / 384, cc = c % 384;
                float bias = (which == 0) ? ld1(bias0, cc, f)
                           : (which == 2) ? ld1(bias2, cc, f) : 0.0f;
                int hh = cc >> 5, dd = cc & 31;
                for (int r = 0; r < 4; ++r) {
                    int m = m0 + rw + mt * 16 + quad * 4 + r;
                    int b = m >> 8, ntok = m & 255;
                    long dst = (long)which * WSQ +
                               (((long)(b * NH + hh) * NT + ntok) * HD + dd);
                    ((ushort_t*)Cout)[dst] = f2bf(acc[mt][nt][r] + bias);
                }
            } else {
                float bias = ld1(bias0, c, f);
                for (int r = 0; r < 4; ++r) {
                    int m = m0 + rw + mt * 16 + quad * 4 + r;
                    float v = acc[mt][nt][r] + bias;
                    long o = (long)m * 384 + c;
                    if (f) ((float*)Cout)[o] = v;
                    else   ((ushort_t*)Cout)[o] = f2bf(v);
                }
            }
        }
    }
}

// ---------------- fused window attention: one block per (b,h), 256 thr / 4 waves ----------------
// Single-pass softmax: rpb pre-shifted by -B_h, p = exp2(fmaf(S,scale,rpb')) straight
// off the S^T MFMA. P never touches LDS (cvt_pk + permlane quad-transpose).
// LDS shrunk to exactly 32 KiB via 16B-granule XOR swizzles (no pads):
//   ks [256][32]: granule g' = g ^ ((row>>1)&3)   (read = 2-way, same as old pad-40)
//   vts [32][256]: granule g' = g ^ (d&7)         (read = 2-way, same as old pad-264)
// -> 5 blocks/CU (163840/32768) = 5 waves/SIMD, was 4. setprio(1) around MFMA
// clusters (barrier-free phase-staggered waves -> m191 regime).
__global__ __launch_bounds__(256, 4) void attn_kernel(
    ushort_t* __restrict__ qkv, const void* __restrict__ ls,
    const float* __restrict__ rpb, const int* __restrict__ fl)
{
    __shared__ __attribute__((aligned(16))) ushort_t ks[256 * 32];    // 16384 B
    __shared__ __attribute__((aligned(16))) ushort_t vts[32 * 256];   // 16384 B

    const int f = *fl;
    // bijective: 3072 = 8 XCD x (12 h x 32 windows); same-h blocks contiguous per XCD
    const int bid = blockIdx.x;
    const int xcd = bid & 7, local = bid >> 3;
    const int h = local >> 5, bwin = (xcd << 5) + (local & 31);
    const int bh = bwin * NH + h;
    ushort_t* qp = qkv + (long)bh * NT * HD;
    const ushort_t* kp = qp + WSQ;
    const ushort_t* vp = qp + 2 * WSQ;
    const int tid = threadIdx.x;
    // logit scale, log2 domain (matches pre-scaled rpb)
    const float scale = __expf(fminf(ld1(ls, h, f), 4.6051702f)) * 1.44269504f;

    // ---- stage K (L2-normalized) and V^T: one token per thread ----
    {
        const int t = tid;
        ushort8 kv[4];
        #pragma unroll
        for (int i = 0; i < 4; ++i) kv[i] = *(const ushort8*)&kp[t * HD + i * 8];
        float fv[32]; float ss = 0.0f;
        #pragma unroll
        for (int i = 0; i < 4; ++i)
            #pragma unroll
            for (int j = 0; j < 8; ++j) {
                float v = bf2f(kv[i][j]); fv[i * 8 + j] = v; ss += v * v;
            }
        float rn = 1.0f / fmaxf(sqrtf(ss), 1e-12f);
        #pragma unroll
        for (int i = 0; i < 4; ++i) {
            uint4v o;
            #pragma unroll
            for (int j = 0; j < 4; ++j)
                o[j] = cvt_pk_bf16(fv[i * 8 + 2 * j] * rn, fv[i * 8 + 2 * j + 1] * rn);
            *(uint4v*)&ks[t * 32 + ((i ^ ((t >> 1) & 3)) << 3)] = o;
        }
        ushort8 vv[4];
        #pragma unroll
        for (int i = 0; i < 4; ++i) vv[i] = *(const ushort8*)&vp[t * HD + i * 8];
        #pragma unroll
        for (int i = 0; i < 4; ++i)
            #pragma unroll
            for (int j = 0; j < 8; ++j) {
                int d = i * 8 + j;
                vts[d * 256 + (((t >> 3) ^ j) << 3) + (t & 7)] = vv[i][j];
            }
    }
    __syncthreads();

    const int w = tid >> 6, lane = tid & 63, l15 = lane & 15, quad = lane >> 4;
    const int ksw = (l15 >> 1) & 3;   // ks read-side granule XOR
    const int vsw = l15 & 7;          // vts read-side granule XOR (d&7 == l15&7)

    if (scale <= 40.0f) {
      // ================= fast path: bound-shifted single-pass softmax =================
      for (int c = 0; c < 4; ++c) {
        const int mloc = w * 64 + c * 16;

        // q fragment: lane holds q[mloc+l15][quad*8..+8]; normalize via shfl
        ushort8 qv = *(const ushort8*)&qp[(mloc + l15) * HD + quad * 8];
        float qf[8]; float ss = 0.0f;
        #pragma unroll
        for (int j = 0; j < 8; ++j) { qf[j] = bf2f(qv[j]); ss += qf[j] * qf[j]; }
        ss += __shfl_xor(ss, 16, 64);
        ss += __shfl_xor(ss, 32, 64);
        float rn = 1.0f / fmaxf(sqrtf(ss), 1e-12f);
        uint4v qa;
        #pragma unroll
        for (int j = 0; j < 4; ++j)
            qa[j] = cvt_pk_bf16(qf[2 * j] * rn, qf[2 * j + 1] * rn);
        short8 aq = __builtin_bit_cast(short8, qa);

        const float* rp = rpb + ((long)h * NT + mloc + l15) * NT;
        const floatx4* rp4 = (const floatx4*)rp;   // strip t, quad -> rp4[t*4+quad]
        floatx4 rb0 = rp4[quad], rb1 = rp4[4 + quad];   // issue before MFMA cluster

        // S^T strip: MFMA(A=k, B=q) -> D[key][token]; lane: token=l15, keys=t*16+quad*4+r
        floatx4 accS[16];
        __builtin_amdgcn_s_setprio(1);
        #pragma unroll
        for (int t = 0; t < 16; ++t) {
            short8 bk = *(short8*)&ks[(t * 16 + l15) * 32 + ((quad ^ ksw) << 3)];
            floatx4 z = {};
            accS[t] = __builtin_amdgcn_mfma_f32_16x16x32_bf16(bk, aq, z, 0, 0, 0);
        }
        __builtin_amdgcn_s_setprio(0);

        // 8 PV phases: fused exp2(fmaf(S,scale,rpb')) + pack + permlane + 2 MFMA.
        float s4[4] = {0.f, 0.f, 0.f, 0.f};
        floatx4 accO[2] = {};
        #pragma unroll
        for (int kk = 0; kk < 8; ++kk) {
            const int vg = ((kk * 4 + quad) ^ vsw) << 3;
            short8 vf0 = *(short8*)&vts[l15 * 256 + vg];
            short8 vf1 = *(short8*)&vts[(16 + l15) * 256 + vg];
            floatx4 nb0 = rb0, nb1 = rb1;
            if (kk < 7) { nb0 = rp4[8 * (kk + 1) + quad]; nb1 = rp4[8 * (kk + 1) + 4 + quad]; }
            const int t0 = 2 * kk, t1 = 2 * kk + 1;
            float a0 = exp2_fast(fmaf(accS[t0][0], scale, rb0[0]));
            float a1 = exp2_fast(fmaf(accS[t0][1], scale, rb0[1]));
            float a2 = exp2_fast(fmaf(accS[t0][2], scale, rb0[2]));
            float a3 = exp2_fast(fmaf(accS[t0][3], scale, rb0[3]));
            float e0 = exp2_fast(fmaf(accS[t1][0], scale, rb1[0]));
            float e1 = exp2_fast(fmaf(accS[t1][1], scale, rb1[1]));
            float e2 = exp2_fast(fmaf(accS[t1][2], scale, rb1[2]));
            float e3 = exp2_fast(fmaf(accS[t1][3], scale, rb1[3]));
            s4[0] += a0 + e0; s4[1] += a1 + e1;
            s4[2] += a2 + e2; s4[3] += a3 + e3;
            uint A0 = cvt_pk_bf16(a0, a1), A1 = cvt_pk_bf16(a2, a3);
            uint B0 = cvt_pk_bf16(e0, e1), B1 = cvt_pk_bf16(e2, e3);
            permlane32_swap(A0, B0); permlane16_swap(A0, B0);
            permlane32_swap(A1, B1); permlane16_swap(A1, B1);
            uint4v pw; pw[0] = A0; pw[1] = A1; pw[2] = B0; pw[3] = B1;
            short8 pf = __builtin_bit_cast(short8, pw);
            __builtin_amdgcn_s_setprio(1);
            accO[0] = __builtin_amdgcn_mfma_f32_16x16x32_bf16(pf, vf0, accO[0], 0, 0, 0);
            accO[1] = __builtin_amdgcn_mfma_f32_16x16x32_bf16(pf, vf1, accO[1], 0, 0, 0);
            __builtin_amdgcn_s_setprio(0);
            rb0 = nb0; rb1 = nb1;
        }

        float rsum = (s4[0] + s4[1]) + (s4[2] + s4[3]);
        rsum += __shfl_xor(rsum, 16, 64);
        rsum += __shfl_xor(rsum, 32, 64);
        float rinv = 1.0f / rsum;
        float ri[4];
        #pragma unroll
        for (int r = 0; r < 4; ++r) ri[r] = __shfl(rinv, quad * 4 + r, 64);

        // epilogue: D[token=quad*4+r][d=tn*16+l15], fold 1/rsum here
        #pragma unroll
        for (int tn = 0; tn < 2; ++tn)
            #pragma unroll
            for (int r = 0; r < 4; r += 2) {
                uint pk = cvt_pk_bf16(accO[tn][r] * ri[r], accO[tn][r + 1] * ri[r + 1]);
                int n = mloc + quad * 4 + r;
                qp[n * HD + tn * 16 + l15] = (ushort_t)pk;
                qp[(n + 1) * HD + tn * 16 + l15] = (ushort_t)(pk >> 16);
            }
      }
    } else {
      // ============ exact-max fallback (scale>40; uniform rpb shift cancels) ============
      for (int c = 0; c < 4; ++c) {
        const int mloc = w * 64 + c * 16;

        ushort8 qv = *(const ushort8*)&qp[(mloc + l15) * HD + quad * 8];
        float qf[8]; float ss = 0.0f;
        #pragma unroll
        for (int j = 0; j < 8; ++j) { qf[j] = bf2f(qv[j]); ss += qf[j] * qf[j]; }
        ss += __shfl_xor(ss, 16, 64);
        ss += __shfl_xor(ss, 32, 64);
        float rn = 1.0f / fmaxf(sqrtf(ss), 1e-12f);
        uint4v qa;
        #pragma unroll
        for (int j = 0; j < 4; ++j)
            qa[j] = cvt_pk_bf16(qf[2 * j] * rn, qf[2 * j + 1] * rn);
        short8 aq = __builtin_bit_cast(short8, qa);

        floatx4 accS[16];
        #pragma unroll
        for (int t = 0; t < 16; ++t) {
            short8 bk = *(short8*)&ks[(t * 16 + l15) * 32 + ((quad ^ ksw) << 3)];
            floatx4 z = {};
            accS[t] = __builtin_amdgcn_mfma_f32_16x16x32_bf16(bk, aq, z, 0, 0, 0);
        }

        const float* rp = rpb + ((long)h * NT + mloc + l15) * NT;
        float m4[4] = {-3e38f, -3e38f, -3e38f, -3e38f};
        #pragma unroll
        for (int t = 0; t < 16; ++t) {
            floatx4 rb = *(const floatx4*)&rp[t * 16 + quad * 4];
            float v0 = fmaf(accS[t][0], scale, rb[0]);
            float v1 = fmaf(accS[t][1], scale, rb[1]);
            float v2 = fmaf(accS[t][2], scale, rb[2]);
            float v3 = fmaf(accS[t][3], scale, rb[3]);
            accS[t][0] = v0; accS[t][1] = v1; accS[t][2] = v2; accS[t][3] = v3;
            m4[t & 3] = fmaxf(m4[t & 3], fmaxf(fmaxf(v0, v1), fmaxf(v2, v3)));
        }
        float rmax = fmaxf(fmaxf(m4[0], m4[1]), fmaxf(m4[2], m4[3]));
        rmax = fmaxf(rmax, __shfl_xor(rmax, 16, 64));
        rmax = fmaxf(rmax, __shfl_xor(rmax, 32, 64));

        float s4[4] = {0.f, 0.f, 0.f, 0.f};
        floatx4 accO[2] = {};
        #pragma unroll
        for (int kk = 0; kk < 8; ++kk) {
            const int vg = ((kk * 4 + quad) ^ vsw) << 3;
            short8 vf0 = *(short8*)&vts[l15 * 256 + vg];
            short8 vf1 = *(short8*)&vts[(16 + l15) * 256 + vg];
            const int t0 = 2 * kk, t1 = 2 * kk + 1;
            float a0 = exp2_fast(accS[t0][0] - rmax);
            float a1 = exp2_fast(accS[t0][1] - rmax);
            float a2 = exp2_fast(accS[t0][2] - rmax);
            float a3 = exp2_fast(accS[t0][3] - rmax);
            float e0 = exp2_fast(accS[t1][0] - rmax);
            float e1 = exp2_fast(accS[t1][1] - rmax);
            float e2 = exp2_fast(accS[t1][2] - rmax);
            float e3 = exp2_fast(accS[t1][3] - rmax);
            s4[0] += a0 + e0; s4[1] += a1 + e1;
            s4[2] += a2 + e2; s4[3] += a3 + e3;
            uint A0 = cvt_pk_bf16(a0, a1), A1 = cvt_pk_bf16(a2, a3);
            uint B0 = cvt_pk_bf16(e0, e1), B1 = cvt_pk_bf16(e2, e3);
            permlane32_swap(A0, B0); permlane16_swap(A0, B0);
            permlane32_swap(A1, B1); permlane16_swap(A1, B1);
            uint4v pw; pw[0] = A0; pw[1] = A1; pw[2] = B0; pw[3] = B1;
            short8 pf = __builtin_bit_cast(short8, pw);
            accO[0] = __builtin_amdgcn_mfma_f32_16x16x32_bf16(pf, vf0, accO[0], 0, 0, 0);
            accO[1] = __builtin_amdgcn_mfma_f32_16x16x32_bf16(pf, vf1, accO[1], 0, 0, 0);
        }

        float rsum = (s4[0] + s4[1]) + (s4[2] + s4[3]);
        rsum += __shfl_xor(rsum, 16, 64);
        rsum += __shfl_xor(rsum, 32, 64);
        float rinv = 1.0f / rsum;
        float ri[4];
        #pragma unroll
        for (int r = 0; r < 4; ++r) ri[r] = __shfl(rinv, quad * 4 + r, 64);

        #pragma unroll
        for (int tn = 0; tn < 2; ++tn)
            #pragma unroll
            for (int r = 0; r < 4; r += 2) {
                uint pk = cvt_pk_bf16(accO[tn][r] * ri[r], accO[tn][r + 1] * ri[r + 1]);
                int n = mloc + quad * 4 + r;
                qp[n * HD + tn * 16 + l15] = (ushort_t)pk;
                qp[(n + 1) * HD + tn * 16 + l15] = (ushort_t)(pk >> 16);
            }
      }
    }
}

extern "C" void kernel_launch(void* const* d_in, const int* in_sizes, int n_in,
                              void* d_out, int out_size, void* d_ws, size_t ws_size,
                              hipStream_t stream)
{
    const void* x      = d_in[0];
    const void* qkv_w  = d_in[1];
    const void* q_bias = d_in[2];
    const void* v_bias = d_in[3];
    const void* lscale = d_in[4];
    const void* cpb_w1 = d_in[5];
    const void* cpb_b1 = d_in[6];
    const void* cpb_w2 = d_in[7];
    const void* proj_w = d_in[8];
    const void* proj_b = d_in[9];
    const void* rct    = d_in[10];
    const int*  rpi    = (const int*)d_in[11];

    char* ws = (char*)d_ws;
    ushort_t* qkv_ws  = (ushort_t*)ws;                          // 3*WSQ bf16 = 150,994,944 B
    float*    bt      = (float*)(ws + 150994944L);              // 961*12 f32
    float*    rpb     = (float*)(ws + 151060480L);              // 12*65536 f32 = 3,145,728 B
    int*      flag    = (int*)(ws + 154206208L);
    ushort_t* wqkv_b  = (ushort_t*)(ws + 154206464L);           // 1152*384 bf16 = 884,736 B
    ushort_t* wproj_b = (ushort_t*)(ws + 155091200L);           // 384*384 bf16 = 294,912 B
    ushort_t* xb      = (ushort_t*)d_out;                       // x in bf16 (50.3 MB scratch,
                                                                // consumed before final store)

    detect_kernel<<<1, 64, 0, stream>>>((const ushort_t*)x, flag);
    cvt_kernel<<<12288, 256, 0, stream>>>(x, xb, flag, 3145728L);      // x: 25,165,824 el
    cvt_kernel<<<216, 256, 0, stream>>>(qkv_w, wqkv_b, flag, 55296L);  // 442,368 el
    cvt_kernel<<<72, 256, 0, stream>>>(proj_w, wproj_b, flag, 18432L); // 147,456 el
    cpb_kernel<<<961, 512, 0, stream>>>(rct, cpb_w1, cpb_b1, cpb_w2, flag, bt);
    rpb_kernel<<<3072, 256, 0, stream>>>(rpi, bt, lscale, flag, rpb);
    gemm_bt<0><<<4608, 256, 0, stream>>>(xb, wqkv_b, q_bias, v_bias, qkv_ws, flag);
    attn_kernel<<<3072, 256, 0, stream>>>(qkv_ws, lscale, rpb, flag);
    gemm_bt<1><<<1536, 256, 0, stream>>>(qkv_ws, wproj_b, proj_b, nullptr, d_out, flag);
}